// Round 1
// baseline (454.462 us; speedup 1.0000x reference)
//
#include <hip/hip_runtime.h>
#include <hip/hip_bf16.h>
#include <math.h>

#define BB    16
#define CDIM  256
#define NN    8192
#define HEADS 4
#define DHEAD 32
#define HID   128
#define LDA   72   // padded LDS row stride (64 + 8 bf16) -> 2-way-max bank aliasing

typedef __bf16 bf16x8 __attribute__((ext_vector_type(8)));
typedef float  f32x4  __attribute__((ext_vector_type(4)));

__device__ __forceinline__ unsigned short f2bf(float f) {
    union { float f; unsigned u; } v; v.f = f;
    unsigned u = v.u;
    return (unsigned short)((u + 0x7fffu + ((u >> 16) & 1u)) >> 16);  // RNE
}

// ---------------- K0a: x[b][c][n] fp32 -> xt[b][n][c] bf16 ----------------
__global__ __launch_bounds__(256) void k_transpose(const float* __restrict__ x,
                                                   unsigned short* __restrict__ xt) {
    __shared__ __align__(16) unsigned short tile[64][68];
    int n0 = blockIdx.x * 64;
    int c0 = blockIdx.y * 64;
    int b  = blockIdx.z;
    const float* xb = x + (size_t)b * CDIM * NN;
    int t = threadIdx.x;
#pragma unroll
    for (int i = 0; i < 4; i++) {
        int idx  = t + 256 * i;
        int row  = idx >> 4;         // c local
        int col4 = (idx & 15) << 2;  // n local
        const float4 v = *(const float4*)(xb + (size_t)(c0 + row) * NN + n0 + col4);
        ushort4 o;
        o.x = f2bf(v.x); o.y = f2bf(v.y); o.z = f2bf(v.z); o.w = f2bf(v.w);
        *(ushort4*)&tile[row][col4] = o;
    }
    __syncthreads();
    unsigned short* xtb = xt + (size_t)b * NN * CDIM;
#pragma unroll
    for (int i = 0; i < 4; i++) {
        int idx  = t + 256 * i;
        int nrow = idx >> 4;
        int cg   = (idx & 15) << 2;
        ushort4 o;
        o.x = tile[cg + 0][nrow]; o.y = tile[cg + 1][nrow];
        o.z = tile[cg + 2][nrow]; o.w = tile[cg + 3][nrow];
        *(ushort4*)(xtb + (size_t)(n0 + nrow) * CDIM + c0 + cg) = o;
    }
}

// ---------------- K0b: w_qkv rows 128..383 (k,v) -> bf16 ----------------
__global__ __launch_bounds__(256) void k_convert_w(const float* __restrict__ w_qkv,
                                                   unsigned short* __restrict__ wkv) {
    int g = blockIdx.x * 256 + threadIdx.x;  // 16384 threads, 4 elems each
    const float4 v = *(const float4*)(w_qkv + (size_t)HID * CDIM + (size_t)g * 4);
    ushort4 o;
    o.x = f2bf(v.x); o.y = f2bf(v.y); o.z = f2bf(v.z); o.w = f2bf(v.w);
    *(ushort4*)(wkv + (size_t)g * 4) = o;
}

// ---------------- K1: [k;v] = W_kv @ x, exp(k), context partials ----------------
// grid (N/64, B), 256 threads (4 waves). Wave w computes rows [w*64, w*64+64).
__global__ __launch_bounds__(256) void k_qkv_ctx(const unsigned short* __restrict__ wkv,
                                                 const unsigned short* __restrict__ xt,
                                                 float* __restrict__ Cg,   // [B][H][32][32]
                                                 float* __restrict__ Sg) { // [B][H][32]
    __shared__ __align__(16) unsigned short As[256 * LDA];  // A tile; reused as kv_s
    __shared__ __align__(16) unsigned short Bs[64 * LDA];
    int n0 = blockIdx.x * 64;
    int b  = blockIdx.y;
    int t = threadIdx.x;
    int w = t >> 6, lane = t & 63, quad = lane >> 4, l16 = lane & 15;

    f32x4 acc[4][4];
#pragma unroll
    for (int i = 0; i < 4; i++)
#pragma unroll
        for (int j = 0; j < 4; j++) acc[i][j] = (f32x4){0.f, 0.f, 0.f, 0.f};

    const unsigned short* xb = xt + (size_t)b * NN * CDIM;

    for (int kt = 0; kt < 4; kt++) {
        int k0 = kt * 64;
        // stage A (W_kv 256x64): 2048 x 16B, 8 per thread
#pragma unroll
        for (int i = 0; i < 8; i++) {
            int vid = t + 256 * i;
            int o   = vid >> 3;
            int kk  = (vid & 7) << 3;
            uint4 v = *(const uint4*)(wkv + (size_t)o * 256 + k0 + kk);
            *(uint4*)&As[o * LDA + kk] = v;
        }
        // stage B (xt 64n x 64k): 512 x 16B, 2 per thread
#pragma unroll
        for (int i = 0; i < 2; i++) {
            int vid = t + 256 * i;
            int nl  = vid >> 3;
            int kk  = (vid & 7) << 3;
            uint4 v = *(const uint4*)(xb + (size_t)(n0 + nl) * CDIM + k0 + kk);
            *(uint4*)&Bs[nl * LDA + kk] = v;
        }
        __syncthreads();
#pragma unroll
        for (int kk = 0; kk < 64; kk += 32) {
            bf16x8 af[4], bfr[4];
#pragma unroll
            for (int mt = 0; mt < 4; mt++)
                af[mt] = *(const bf16x8*)&As[(w * 64 + mt * 16 + l16) * LDA + kk + quad * 8];
#pragma unroll
            for (int nt = 0; nt < 4; nt++)
                bfr[nt] = *(const bf16x8*)&Bs[(nt * 16 + l16) * LDA + kk + quad * 8];
#pragma unroll
            for (int mt = 0; mt < 4; mt++)
#pragma unroll
                for (int nt = 0; nt < 4; nt++)
                    acc[mt][nt] = __builtin_amdgcn_mfma_f32_16x16x32_bf16(af[mt], bfr[nt], acc[mt][nt], 0, 0, 0);
        }
        __syncthreads();
    }

    // Epilogue: write exp(k) / v into kv_s (alias of As), accumulate row exp-sums.
    unsigned short* kvs = As;
    float sexp[4][4];
    bool isK = (w < 2);
#pragma unroll
    for (int mt = 0; mt < 4; mt++) {
#pragma unroll
        for (int reg = 0; reg < 4; reg++) {
            int o = w * 64 + mt * 16 + quad * 4 + reg;
            float s = 0.f;
#pragma unroll
            for (int nt = 0; nt < 4; nt++) {
                float v = acc[mt][nt][reg];
                if (isK) { v = __expf(v); s += v; }
                kvs[o * LDA + nt * 16 + l16] = f2bf(v);
            }
            sexp[mt][reg] = s;
        }
    }
    if (isK) {
#pragma unroll
        for (int mt = 0; mt < 4; mt++)
#pragma unroll
            for (int reg = 0; reg < 4; reg++) {
                float s = sexp[mt][reg];
                s += __shfl_xor(s, 1, 64);
                s += __shfl_xor(s, 2, 64);
                s += __shfl_xor(s, 4, 64);
                s += __shfl_xor(s, 8, 64);
                if (l16 == 0) {
                    int o = w * 64 + mt * 16 + quad * 4 + reg;  // k row index 0..127
                    atomicAdd(&Sg[(b * HEADS + (o >> 5)) * DHEAD + (o & 31)], s);
                }
            }
    }
    __syncthreads();

    // Context partial: wave w handles head h = w. C_part = P(32xCN) @ V^T(CNx32), K = 64 n.
    {
        int h = w;
        f32x4 cacc[2][2];
#pragma unroll
        for (int i = 0; i < 2; i++)
#pragma unroll
            for (int j = 0; j < 2; j++) cacc[i][j] = (f32x4){0.f, 0.f, 0.f, 0.f};
#pragma unroll
        for (int nk = 0; nk < 64; nk += 32) {
            bf16x8 pa[2], vb[2];
#pragma unroll
            for (int dt = 0; dt < 2; dt++)
                pa[dt] = *(const bf16x8*)&kvs[(h * 32 + dt * 16 + l16) * LDA + nk + quad * 8];
#pragma unroll
            for (int et = 0; et < 2; et++)
                vb[et] = *(const bf16x8*)&kvs[(128 + h * 32 + et * 16 + l16) * LDA + nk + quad * 8];
#pragma unroll
            for (int dt = 0; dt < 2; dt++)
#pragma unroll
                for (int et = 0; et < 2; et++)
                    cacc[dt][et] = __builtin_amdgcn_mfma_f32_16x16x32_bf16(pa[dt], vb[et], cacc[dt][et], 0, 0, 0);
        }
        float* Cb = Cg + (size_t)(b * HEADS + h) * 32 * 32;
#pragma unroll
        for (int dt = 0; dt < 2; dt++)
#pragma unroll
            for (int et = 0; et < 2; et++)
#pragma unroll
                for (int reg = 0; reg < 4; reg++) {
                    int d = dt * 16 + quad * 4 + reg;
                    int e = et * 16 + l16;
                    atomicAdd(&Cb[d * 32 + e], cacc[dt][et][reg]);
                }
    }
}

// ---------------- K2: M[b] = (w_out ∘ ctx) @ W_q  (256x256 bf16 per batch) ----------------
// grid (16 o-tiles, B), 256 threads.
__global__ __launch_bounds__(256) void k_build_m(const float* __restrict__ w_out,
                                                 const float* __restrict__ w_qkv,
                                                 const float* __restrict__ Cg,
                                                 const float* __restrict__ Sg,
                                                 unsigned short* __restrict__ Mb) {
    __shared__ float Arow[16][128];
    int ot = blockIdx.x;
    int b  = blockIdx.y;
    int t  = threadIdx.x;
    const float* Cb = Cg + (size_t)b * HEADS * 32 * 32;
    const float* Sb = Sg + (size_t)b * HEADS * 32;
#pragma unroll
    for (int i = 0; i < 8; i++) {
        int ent = t + 256 * i;         // 2048 entries: 16 o x 128 hd
        int ol  = ent >> 7;
        int hd  = ent & 127;
        int h = hd >> 5, d = hd & 31;
        const float* wo = w_out + (size_t)(ot * 16 + ol) * HID + h * 32;
        const float* cc = Cb + (h * 32 + d) * 32;
        float s = 0.f;
#pragma unroll
        for (int e = 0; e < 32; e++) s += wo[e] * cc[e];
        Arow[ol][hd] = s / Sb[h * 32 + d];
    }
    __syncthreads();
    unsigned short* Mo = Mb + (size_t)b * CDIM * CDIM;
#pragma unroll
    for (int i = 0; i < 16; i++) {
        int ol = i;
        int c  = t;
        float s = 0.f;
#pragma unroll 8
        for (int hd = 0; hd < 128; hd++) s += Arow[ol][hd] * w_qkv[(size_t)hd * CDIM + c];
        Mo[(size_t)(ot * 16 + ol) * CDIM + c] = f2bf(s);
    }
}

// ---------------- K3: out[b] = M[b] @ x[b] + b_out ----------------
__global__ __launch_bounds__(256) void k_out_gemm(const unsigned short* __restrict__ Mb,
                                                  const unsigned short* __restrict__ xt,
                                                  const float* __restrict__ b_out,
                                                  float* __restrict__ out) {
    __shared__ __align__(16) unsigned short As[256 * LDA];
    __shared__ __align__(16) unsigned short Bs[64 * LDA];
    int n0 = blockIdx.x * 64;
    int b  = blockIdx.y;
    int t = threadIdx.x;
    int w = t >> 6, lane = t & 63, quad = lane >> 4, l16 = lane & 15;

    f32x4 acc[4][4];
#pragma unroll
    for (int i = 0; i < 4; i++)
#pragma unroll
        for (int j = 0; j < 4; j++) acc[i][j] = (f32x4){0.f, 0.f, 0.f, 0.f};

    const unsigned short* Ab = Mb + (size_t)b * CDIM * CDIM;
    const unsigned short* xb = xt + (size_t)b * NN * CDIM;

    for (int kt = 0; kt < 4; kt++) {
        int k0 = kt * 64;
#pragma unroll
        for (int i = 0; i < 8; i++) {
            int vid = t + 256 * i;
            int o   = vid >> 3;
            int kk  = (vid & 7) << 3;
            uint4 v = *(const uint4*)(Ab + (size_t)o * 256 + k0 + kk);
            *(uint4*)&As[o * LDA + kk] = v;
        }
#pragma unroll
        for (int i = 0; i < 2; i++) {
            int vid = t + 256 * i;
            int nl  = vid >> 3;
            int kk  = (vid & 7) << 3;
            uint4 v = *(const uint4*)(xb + (size_t)(n0 + nl) * CDIM + k0 + kk);
            *(uint4*)&Bs[nl * LDA + kk] = v;
        }
        __syncthreads();
#pragma unroll
        for (int kk = 0; kk < 64; kk += 32) {
            bf16x8 af[4], bfr[4];
#pragma unroll
            for (int mt = 0; mt < 4; mt++)
                af[mt] = *(const bf16x8*)&As[(w * 64 + mt * 16 + l16) * LDA + kk + quad * 8];
#pragma unroll
            for (int nt = 0; nt < 4; nt++)
                bfr[nt] = *(const bf16x8*)&Bs[(nt * 16 + l16) * LDA + kk + quad * 8];
#pragma unroll
            for (int mt = 0; mt < 4; mt++)
#pragma unroll
                for (int nt = 0; nt < 4; nt++)
                    acc[mt][nt] = __builtin_amdgcn_mfma_f32_16x16x32_bf16(af[mt], bfr[nt], acc[mt][nt], 0, 0, 0);
        }
        __syncthreads();
    }

    float* ob = out + (size_t)b * CDIM * NN;
#pragma unroll
    for (int mt = 0; mt < 4; mt++)
#pragma unroll
        for (int reg = 0; reg < 4; reg++) {
            int o = w * 64 + mt * 16 + quad * 4 + reg;
            float bo = b_out[o];
#pragma unroll
            for (int nt = 0; nt < 4; nt++)
                ob[(size_t)o * NN + n0 + nt * 16 + l16] = acc[mt][nt][reg] + bo;
        }
}

// ---------------- launch ----------------
extern "C" void kernel_launch(void* const* d_in, const int* in_sizes, int n_in,
                              void* d_out, int out_size, void* d_ws, size_t ws_size,
                              hipStream_t stream) {
    const float* x     = (const float*)d_in[0];
    const float* w_qkv = (const float*)d_in[1];
    const float* w_out = (const float*)d_in[2];
    const float* b_out = (const float*)d_in[3];
    float* out = (float*)d_out;

    char* ws = (char*)d_ws;
    const size_t off_xt  = 0;                       // 16*8192*256*2 = 67108864
    const size_t off_wkv = off_xt + 67108864;       // 256*256*2     = 131072
    const size_t off_C   = off_wkv + 131072;        // 16*4*32*32*4  = 262144
    const size_t off_S   = off_C + 262144;          // 16*4*32*4     = 8192
    const size_t off_M   = off_S + 8192;            // 16*256*256*2  = 2097152

    unsigned short* xt  = (unsigned short*)(ws + off_xt);
    unsigned short* wkv = (unsigned short*)(ws + off_wkv);
    float*          Cg  = (float*)(ws + off_C);
    float*          Sg  = (float*)(ws + off_S);
    unsigned short* Mb  = (unsigned short*)(ws + off_M);

    hipMemsetAsync(Cg, 0, 262144 + 8192, stream);
    k_transpose<<<dim3(NN / 64, CDIM / 64, BB), 256, 0, stream>>>(x, xt);
    k_convert_w<<<dim3(64), 256, 0, stream>>>(w_qkv, wkv);
    k_qkv_ctx<<<dim3(NN / 64, BB), 256, 0, stream>>>(wkv, xt, Cg, Sg);
    k_build_m<<<dim3(16, BB), 256, 0, stream>>>(w_out, w_qkv, Cg, Sg, Mb);
    k_out_gemm<<<dim3(NN / 64, BB), 256, 0, stream>>>(Mb, xt, b_out, out);
}

// Round 2
// 389.694 us; speedup vs baseline: 1.1662x; 1.1662x over previous
//
#include <hip/hip_runtime.h>
#include <hip/hip_bf16.h>
#include <math.h>

#define BB     16
#define CDIM   256
#define NN     8192
#define HEADS  4
#define DHEAD  32
#define HID    128
#define LDA    72    // padded LDS row stride (64 + 8 bf16) -> benign 2-way bank aliasing
#define NCHUNK 256   // n-cols per k_qkv_ctx block (4 sub-tiles of 64)
#define SLOTS  32    // NN / NCHUNK partial-reduction slots per batch

typedef __bf16 bf16x8 __attribute__((ext_vector_type(8)));
typedef float  f32x4  __attribute__((ext_vector_type(4)));

__device__ __forceinline__ unsigned short f2bf(float f) {
    union { float f; unsigned u; } v; v.f = f;
    unsigned u = v.u;
    return (unsigned short)((u + 0x7fffu + ((u >> 16) & 1u)) >> 16);  // RNE
}

// ---------------- K0a: x[b][c][n] fp32 -> xt[b][n][c] bf16 ----------------
__global__ __launch_bounds__(256) void k_transpose(const float* __restrict__ x,
                                                   unsigned short* __restrict__ xt) {
    __shared__ __align__(16) unsigned short tile[64][68];
    int n0 = blockIdx.x * 64;
    int c0 = blockIdx.y * 64;
    int b  = blockIdx.z;
    const float* xb = x + (size_t)b * CDIM * NN;
    int t = threadIdx.x;
#pragma unroll
    for (int i = 0; i < 4; i++) {
        int idx  = t + 256 * i;
        int row  = idx >> 4;         // c local
        int col4 = (idx & 15) << 2;  // n local
        const float4 v = *(const float4*)(xb + (size_t)(c0 + row) * NN + n0 + col4);
        ushort4 o;
        o.x = f2bf(v.x); o.y = f2bf(v.y); o.z = f2bf(v.z); o.w = f2bf(v.w);
        *(ushort4*)&tile[row][col4] = o;
    }
    __syncthreads();
    unsigned short* xtb = xt + (size_t)b * NN * CDIM;
#pragma unroll
    for (int i = 0; i < 4; i++) {
        int idx  = t + 256 * i;
        int nrow = idx >> 4;
        int cg   = (idx & 15) << 2;
        ushort4 o;
        o.x = tile[cg + 0][nrow]; o.y = tile[cg + 1][nrow];
        o.z = tile[cg + 2][nrow]; o.w = tile[cg + 3][nrow];
        *(ushort4*)(xtb + (size_t)(n0 + nrow) * CDIM + c0 + cg) = o;
    }
}

// ---------------- K0b: w_qkv rows 128..383 (k,v) -> bf16 ----------------
__global__ __launch_bounds__(256) void k_convert_w(const float* __restrict__ w_qkv,
                                                   unsigned short* __restrict__ wkv) {
    int g = blockIdx.x * 256 + threadIdx.x;  // 16384 threads, 4 elems each
    const float4 v = *(const float4*)(w_qkv + (size_t)HID * CDIM + (size_t)g * 4);
    ushort4 o;
    o.x = f2bf(v.x); o.y = f2bf(v.y); o.z = f2bf(v.z); o.w = f2bf(v.w);
    *(ushort4*)(wkv + (size_t)g * 4) = o;
}

// ---------------- K1: [k;v] = W_kv @ x, exp(k), context partials (NO atomics) ---------
// grid (SLOTS, B), 256 threads (4 waves). Wave w computes kv rows [w*64, w*64+64).
// Each block covers NCHUNK=256 n-cols as 4 sub-tiles of 64; context accumulates in
// registers across sub-tiles; block-private partial slabs written at the end.
__global__ __launch_bounds__(256) void k_qkv_ctx(const unsigned short* __restrict__ wkv,
                                                 const unsigned short* __restrict__ xt,
                                                 float* __restrict__ Cpart,   // [B][SLOTS][H][32*32]
                                                 float* __restrict__ Spart) { // [B][SLOTS][128]
    __shared__ __align__(16) unsigned short As[256 * LDA];  // A tile; reused as kv_s
    __shared__ __align__(16) unsigned short Bs[64 * LDA];
    int slot = blockIdx.x;
    int b    = blockIdx.y;
    int t = threadIdx.x;
    int w = t >> 6, lane = t & 63, quad = lane >> 4, l16 = lane & 15;
    bool isK = (w < 2);

    f32x4 cacc[2][2];
#pragma unroll
    for (int i = 0; i < 2; i++)
#pragma unroll
        for (int j = 0; j < 2; j++) cacc[i][j] = (f32x4){0.f, 0.f, 0.f, 0.f};
    float sexpA[4][4];
#pragma unroll
    for (int i = 0; i < 4; i++)
#pragma unroll
        for (int j = 0; j < 4; j++) sexpA[i][j] = 0.f;

    const unsigned short* xb = xt + (size_t)b * NN * CDIM;
    unsigned short* kvs = As;

    for (int s = 0; s < 4; s++) {
        int n0 = slot * NCHUNK + s * 64;

        f32x4 acc[4][4];
#pragma unroll
        for (int i = 0; i < 4; i++)
#pragma unroll
            for (int j = 0; j < 4; j++) acc[i][j] = (f32x4){0.f, 0.f, 0.f, 0.f};

        for (int kt = 0; kt < 4; kt++) {
            int k0 = kt * 64;
            // stage A (W_kv 256x64): 2048 x 16B, 8 per thread
#pragma unroll
            for (int i = 0; i < 8; i++) {
                int vid = t + 256 * i;
                int o   = vid >> 3;
                int kk  = (vid & 7) << 3;
                uint4 v = *(const uint4*)(wkv + (size_t)o * 256 + k0 + kk);
                *(uint4*)&As[o * LDA + kk] = v;
            }
            // stage B (xt 64n x 64k): 512 x 16B, 2 per thread
#pragma unroll
            for (int i = 0; i < 2; i++) {
                int vid = t + 256 * i;
                int nl  = vid >> 3;
                int kk  = (vid & 7) << 3;
                uint4 v = *(const uint4*)(xb + (size_t)(n0 + nl) * CDIM + k0 + kk);
                *(uint4*)&Bs[nl * LDA + kk] = v;
            }
            __syncthreads();
#pragma unroll
            for (int kk = 0; kk < 64; kk += 32) {
                bf16x8 af[4], bfr[4];
#pragma unroll
                for (int mt = 0; mt < 4; mt++)
                    af[mt] = *(const bf16x8*)&As[(w * 64 + mt * 16 + l16) * LDA + kk + quad * 8];
#pragma unroll
                for (int nt = 0; nt < 4; nt++)
                    bfr[nt] = *(const bf16x8*)&Bs[(nt * 16 + l16) * LDA + kk + quad * 8];
#pragma unroll
                for (int mt = 0; mt < 4; mt++)
#pragma unroll
                    for (int nt = 0; nt < 4; nt++)
                        acc[mt][nt] = __builtin_amdgcn_mfma_f32_16x16x32_bf16(af[mt], bfr[nt], acc[mt][nt], 0, 0, 0);
            }
            __syncthreads();
        }

        // Epilogue: write exp(k) / v into kv_s (alias of As), accumulate row exp-sums.
#pragma unroll
        for (int mt = 0; mt < 4; mt++) {
#pragma unroll
            for (int reg = 0; reg < 4; reg++) {
                int o = w * 64 + mt * 16 + quad * 4 + reg;
#pragma unroll
                for (int nt = 0; nt < 4; nt++) {
                    float v = acc[mt][nt][reg];
                    if (isK) { v = __expf(v); sexpA[mt][reg] += v; }
                    kvs[o * LDA + nt * 16 + l16] = f2bf(v);
                }
            }
        }
        __syncthreads();

        // Context partial: wave w = head h. C_part += P(32x64n) @ V^T(64nx32).
        {
            int h = w;
#pragma unroll
            for (int nk = 0; nk < 64; nk += 32) {
                bf16x8 pa[2], vb[2];
#pragma unroll
                for (int dt = 0; dt < 2; dt++)
                    pa[dt] = *(const bf16x8*)&kvs[(h * 32 + dt * 16 + l16) * LDA + nk + quad * 8];
#pragma unroll
                for (int et = 0; et < 2; et++)
                    vb[et] = *(const bf16x8*)&kvs[(128 + h * 32 + et * 16 + l16) * LDA + nk + quad * 8];
#pragma unroll
                for (int dt = 0; dt < 2; dt++)
#pragma unroll
                    for (int et = 0; et < 2; et++)
                        cacc[dt][et] = __builtin_amdgcn_mfma_f32_16x16x32_bf16(pa[dt], vb[et], cacc[dt][et], 0, 0, 0);
            }
        }
        __syncthreads();  // guard kvs reads before next sub-tile overwrites As
    }

    // Write block-private partials (streaming, no contention).
    float* Cb = Cpart + ((size_t)(b * SLOTS + slot) * HEADS + w) * 1024;
#pragma unroll
    for (int dt = 0; dt < 2; dt++)
#pragma unroll
        for (int et = 0; et < 2; et++)
#pragma unroll
            for (int reg = 0; reg < 4; reg++) {
                int d = dt * 16 + quad * 4 + reg;
                int e = et * 16 + l16;
                Cb[d * 32 + e] = cacc[dt][et][reg];
            }
    if (isK) {
#pragma unroll
        for (int mt = 0; mt < 4; mt++)
#pragma unroll
            for (int reg = 0; reg < 4; reg++) {
                float s = sexpA[mt][reg];
                s += __shfl_xor(s, 1, 64);
                s += __shfl_xor(s, 2, 64);
                s += __shfl_xor(s, 4, 64);
                s += __shfl_xor(s, 8, 64);
                if (l16 == 0) {
                    int o = w * 64 + mt * 16 + quad * 4 + reg;  // k row index 0..127
                    Spart[((size_t)b * SLOTS + slot) * 128 + o] = s;
                }
            }
    }
}

// ---------------- K1b: reduce slots -> Cg, Sinv ----------------
// grid (4, HEADS, B), 256 threads. Block (q,h,b) reduces 256 ctx elems over SLOTS.
__global__ __launch_bounds__(256) void k_reduce(const float* __restrict__ Cpart,
                                                const float* __restrict__ Spart,
                                                float* __restrict__ Cg,     // [B][H][32*32]
                                                float* __restrict__ Sinv) { // [B][H][32]
    int q = blockIdx.x, h = blockIdx.y, b = blockIdx.z;
    int t = threadIdx.x;
    int e = q * 256 + t;
    float acc = 0.f;
#pragma unroll 4
    for (int sl = 0; sl < SLOTS; sl++)
        acc += Cpart[((size_t)(b * SLOTS + sl) * HEADS + h) * 1024 + e];
    Cg[((size_t)b * HEADS + h) * 1024 + e] = acc;
    if (q == 0 && t < 32) {
        float s = 0.f;
#pragma unroll 4
        for (int sl = 0; sl < SLOTS; sl++)
            s += Spart[((size_t)b * SLOTS + sl) * 128 + h * 32 + t];
        Sinv[((size_t)b * HEADS + h) * 32 + t] = 1.0f / s;
    }
}

// ---------------- K2: M[b] = (w_out ∘ ctx) @ W_q  (256x256 bf16 per batch) ----------------
// grid (16 o-tiles, B), 256 threads.
__global__ __launch_bounds__(256) void k_build_m(const float* __restrict__ w_out,
                                                 const float* __restrict__ w_qkv,
                                                 const float* __restrict__ Cg,
                                                 const float* __restrict__ Sinv,
                                                 unsigned short* __restrict__ Mb) {
    __shared__ float Arow[16][128];
    int ot = blockIdx.x;
    int b  = blockIdx.y;
    int t  = threadIdx.x;
    const float* Cb = Cg + (size_t)b * HEADS * 32 * 32;
    const float* Sb = Sinv + (size_t)b * HEADS * 32;
#pragma unroll
    for (int i = 0; i < 8; i++) {
        int ent = t + 256 * i;         // 2048 entries: 16 o x 128 hd
        int ol  = ent >> 7;
        int hd  = ent & 127;
        int h = hd >> 5, d = hd & 31;
        const float* wo = w_out + (size_t)(ot * 16 + ol) * HID + h * 32;
        const float* cc = Cb + (h * 32 + d) * 32;
        float s = 0.f;
#pragma unroll
        for (int e = 0; e < 32; e++) s += wo[e] * cc[e];
        Arow[ol][hd] = s * Sb[h * 32 + d];
    }
    __syncthreads();
    unsigned short* Mo = Mb + (size_t)b * CDIM * CDIM;
#pragma unroll
    for (int i = 0; i < 16; i++) {
        int ol = i;
        int c  = t;
        float s = 0.f;
#pragma unroll 8
        for (int hd = 0; hd < 128; hd++) s += Arow[ol][hd] * w_qkv[(size_t)hd * CDIM + c];
        Mo[(size_t)(ot * 16 + ol) * CDIM + c] = f2bf(s);
    }
}

// ---------------- K3: out[b] = M[b] @ x[b] + b_out ----------------
__global__ __launch_bounds__(256) void k_out_gemm(const unsigned short* __restrict__ Mb,
                                                  const unsigned short* __restrict__ xt,
                                                  const float* __restrict__ b_out,
                                                  float* __restrict__ out) {
    __shared__ __align__(16) unsigned short As[256 * LDA];
    __shared__ __align__(16) unsigned short Bs[64 * LDA];
    int n0 = blockIdx.x * 64;
    int b  = blockIdx.y;
    int t = threadIdx.x;
    int w = t >> 6, lane = t & 63, quad = lane >> 4, l16 = lane & 15;

    f32x4 acc[4][4];
#pragma unroll
    for (int i = 0; i < 4; i++)
#pragma unroll
        for (int j = 0; j < 4; j++) acc[i][j] = (f32x4){0.f, 0.f, 0.f, 0.f};

    const unsigned short* Ab = Mb + (size_t)b * CDIM * CDIM;
    const unsigned short* xb = xt + (size_t)b * NN * CDIM;

    for (int kt = 0; kt < 4; kt++) {
        int k0 = kt * 64;
#pragma unroll
        for (int i = 0; i < 8; i++) {
            int vid = t + 256 * i;
            int o   = vid >> 3;
            int kk  = (vid & 7) << 3;
            uint4 v = *(const uint4*)(Ab + (size_t)o * 256 + k0 + kk);
            *(uint4*)&As[o * LDA + kk] = v;
        }
#pragma unroll
        for (int i = 0; i < 2; i++) {
            int vid = t + 256 * i;
            int nl  = vid >> 3;
            int kk  = (vid & 7) << 3;
            uint4 v = *(const uint4*)(xb + (size_t)(n0 + nl) * CDIM + k0 + kk);
            *(uint4*)&Bs[nl * LDA + kk] = v;
        }
        __syncthreads();
#pragma unroll
        for (int kk = 0; kk < 64; kk += 32) {
            bf16x8 af[4], bfr[4];
#pragma unroll
            for (int mt = 0; mt < 4; mt++)
                af[mt] = *(const bf16x8*)&As[(w * 64 + mt * 16 + l16) * LDA + kk + quad * 8];
#pragma unroll
            for (int nt = 0; nt < 4; nt++)
                bfr[nt] = *(const bf16x8*)&Bs[(nt * 16 + l16) * LDA + kk + quad * 8];
#pragma unroll
            for (int mt = 0; mt < 4; mt++)
#pragma unroll
                for (int nt = 0; nt < 4; nt++)
                    acc[mt][nt] = __builtin_amdgcn_mfma_f32_16x16x32_bf16(af[mt], bfr[nt], acc[mt][nt], 0, 0, 0);
        }
        __syncthreads();
    }

    float* ob = out + (size_t)b * CDIM * NN;
#pragma unroll
    for (int mt = 0; mt < 4; mt++)
#pragma unroll
        for (int reg = 0; reg < 4; reg++) {
            int o = w * 64 + mt * 16 + quad * 4 + reg;
            float bo = b_out[o];
#pragma unroll
            for (int nt = 0; nt < 4; nt++)
                ob[(size_t)o * NN + n0 + nt * 16 + l16] = acc[mt][nt][reg] + bo;
        }
}

// ---------------- launch ----------------
extern "C" void kernel_launch(void* const* d_in, const int* in_sizes, int n_in,
                              void* d_out, int out_size, void* d_ws, size_t ws_size,
                              hipStream_t stream) {
    const float* x     = (const float*)d_in[0];
    const float* w_qkv = (const float*)d_in[1];
    const float* w_out = (const float*)d_in[2];
    const float* b_out = (const float*)d_in[3];
    float* out = (float*)d_out;

    char* ws = (char*)d_ws;
    const size_t off_xt    = 0;                          // 16*8192*256*2      = 67108864
    const size_t off_wkv   = off_xt + 67108864;          // 256*256*2          = 131072
    const size_t off_Cpart = off_wkv + 131072;           // 16*32*4*1024*4     = 8388608
    const size_t off_Spart = off_Cpart + 8388608;        // 16*32*128*4        = 262144
    const size_t off_Cg    = off_Spart + 262144;         // 16*4*1024*4        = 262144
    const size_t off_Sinv  = off_Cg + 262144;            // 16*4*32*4          = 8192
    const size_t off_M     = off_Sinv + 8192;            // 16*256*256*2       = 2097152

    unsigned short* xt    = (unsigned short*)(ws + off_xt);
    unsigned short* wkv   = (unsigned short*)(ws + off_wkv);
    float*          Cpart = (float*)(ws + off_Cpart);
    float*          Spart = (float*)(ws + off_Spart);
    float*          Cg    = (float*)(ws + off_Cg);
    float*          Sinv  = (float*)(ws + off_Sinv);
    unsigned short* Mb    = (unsigned short*)(ws + off_M);

    k_transpose<<<dim3(NN / 64, CDIM / 64, BB), 256, 0, stream>>>(x, xt);
    k_convert_w<<<dim3(64), 256, 0, stream>>>(w_qkv, wkv);
    k_qkv_ctx<<<dim3(SLOTS, BB), 256, 0, stream>>>(wkv, xt, Cpart, Spart);
    k_reduce<<<dim3(4, HEADS, BB), 256, 0, stream>>>(Cpart, Spart, Cg, Sinv);
    k_build_m<<<dim3(16, BB), 256, 0, stream>>>(w_out, w_qkv, Cg, Sinv, Mb);
    k_out_gemm<<<dim3(NN / 64, BB), 256, 0, stream>>>(Mb, xt, b_out, out);
}

// Round 3
// 370.479 us; speedup vs baseline: 1.2267x; 1.0519x over previous
//
#include <hip/hip_runtime.h>
#include <hip/hip_bf16.h>
#include <math.h>

#define BB     16
#define CDIM   256
#define NN     8192
#define HEADS  4
#define DHEAD  32
#define HID    128
#define LDA    72    // padded LDS row stride (64 + 8 bf16) -> benign 2-way bank aliasing
#define NCHUNK 128   // n-cols per k_qkv_ctx block (2 sub-tiles of 64)
#define SLOTS  64    // NN / NCHUNK partial-reduction slots per batch

typedef __bf16 bf16x8 __attribute__((ext_vector_type(8)));
typedef float  f32x4  __attribute__((ext_vector_type(4)));

__device__ __forceinline__ unsigned short f2bf(float f) {
    union { float f; unsigned u; } v; v.f = f;
    unsigned u = v.u;
    return (unsigned short)((u + 0x7fffu + ((u >> 16) & 1u)) >> 16);  // RNE
}

// ---------------- K0a: x[b][c][n] fp32 -> xt[b][n][c] bf16 ----------------
__global__ __launch_bounds__(256) void k_transpose(const float* __restrict__ x,
                                                   unsigned short* __restrict__ xt) {
    __shared__ __align__(16) unsigned short tile[64][68];
    int n0 = blockIdx.x * 64;
    int c0 = blockIdx.y * 64;
    int b  = blockIdx.z;
    const float* xb = x + (size_t)b * CDIM * NN;
    int t = threadIdx.x;
#pragma unroll
    for (int i = 0; i < 4; i++) {
        int idx  = t + 256 * i;
        int row  = idx >> 4;         // c local
        int col4 = (idx & 15) << 2;  // n local
        const float4 v = *(const float4*)(xb + (size_t)(c0 + row) * NN + n0 + col4);
        ushort4 o;
        o.x = f2bf(v.x); o.y = f2bf(v.y); o.z = f2bf(v.z); o.w = f2bf(v.w);
        *(ushort4*)&tile[row][col4] = o;
    }
    __syncthreads();
    unsigned short* xtb = xt + (size_t)b * NN * CDIM;
#pragma unroll
    for (int i = 0; i < 4; i++) {
        int idx  = t + 256 * i;
        int nrow = idx >> 4;
        int cg   = (idx & 15) << 2;
        ushort4 o;
        o.x = tile[cg + 0][nrow]; o.y = tile[cg + 1][nrow];
        o.z = tile[cg + 2][nrow]; o.w = tile[cg + 3][nrow];
        *(ushort4*)(xtb + (size_t)(n0 + nrow) * CDIM + c0 + cg) = o;
    }
}

// ---------------- K0b: w_qkv rows 128..383 (k,v) -> bf16 ----------------
__global__ __launch_bounds__(256) void k_convert_w(const float* __restrict__ w_qkv,
                                                   unsigned short* __restrict__ wkv) {
    int g = blockIdx.x * 256 + threadIdx.x;  // 16384 threads, 4 elems each
    const float4 v = *(const float4*)(w_qkv + (size_t)HID * CDIM + (size_t)g * 4);
    ushort4 o;
    o.x = f2bf(v.x); o.y = f2bf(v.y); o.z = f2bf(v.z); o.w = f2bf(v.w);
    *(ushort4*)(wkv + (size_t)g * 4) = o;
}

// ---------------- K1: [k;v] = W_kv @ x, exp(k), context partials (NO atomics) ---------
// grid (SLOTS, B), 256 threads (4 waves). Wave w computes kv rows [w*64, w*64+64).
// Each block covers NCHUNK=128 n-cols as 2 sub-tiles of 64; context accumulates in
// registers across sub-tiles; block-private partial slabs written at the end.
__global__ __launch_bounds__(256) void k_qkv_ctx(const unsigned short* __restrict__ wkv,
                                                 const unsigned short* __restrict__ xt,
                                                 float* __restrict__ Cpart,   // [B][SLOTS][H][32*32]
                                                 float* __restrict__ Spart) { // [B][SLOTS][128]
    __shared__ __align__(16) unsigned short As[256 * LDA];  // A tile; reused as kv_s
    __shared__ __align__(16) unsigned short Bs[64 * LDA];
    int slot = blockIdx.x;
    int b    = blockIdx.y;
    int t = threadIdx.x;
    int w = t >> 6, lane = t & 63, quad = lane >> 4, l16 = lane & 15;
    bool isK = (w < 2);

    f32x4 cacc[2][2];
#pragma unroll
    for (int i = 0; i < 2; i++)
#pragma unroll
        for (int j = 0; j < 2; j++) cacc[i][j] = (f32x4){0.f, 0.f, 0.f, 0.f};
    float sexpA[4][4];
#pragma unroll
    for (int i = 0; i < 4; i++)
#pragma unroll
        for (int j = 0; j < 4; j++) sexpA[i][j] = 0.f;

    const unsigned short* xb = xt + (size_t)b * NN * CDIM;
    unsigned short* kvs = As;

    for (int s = 0; s < NCHUNK / 64; s++) {
        int n0 = slot * NCHUNK + s * 64;

        f32x4 acc[4][4];
#pragma unroll
        for (int i = 0; i < 4; i++)
#pragma unroll
            for (int j = 0; j < 4; j++) acc[i][j] = (f32x4){0.f, 0.f, 0.f, 0.f};

        for (int kt = 0; kt < 4; kt++) {
            int k0 = kt * 64;
            // stage A (W_kv 256x64): 2048 x 16B, 8 per thread
#pragma unroll
            for (int i = 0; i < 8; i++) {
                int vid = t + 256 * i;
                int o   = vid >> 3;
                int kk  = (vid & 7) << 3;
                uint4 v = *(const uint4*)(wkv + (size_t)o * 256 + k0 + kk);
                *(uint4*)&As[o * LDA + kk] = v;
            }
            // stage B (xt 64n x 64k): 512 x 16B, 2 per thread
#pragma unroll
            for (int i = 0; i < 2; i++) {
                int vid = t + 256 * i;
                int nl  = vid >> 3;
                int kk  = (vid & 7) << 3;
                uint4 v = *(const uint4*)(xb + (size_t)(n0 + nl) * CDIM + k0 + kk);
                *(uint4*)&Bs[nl * LDA + kk] = v;
            }
            __syncthreads();
#pragma unroll
            for (int kk = 0; kk < 64; kk += 32) {
                bf16x8 af[4], bfr[4];
#pragma unroll
                for (int mt = 0; mt < 4; mt++)
                    af[mt] = *(const bf16x8*)&As[(w * 64 + mt * 16 + l16) * LDA + kk + quad * 8];
#pragma unroll
                for (int nt = 0; nt < 4; nt++)
                    bfr[nt] = *(const bf16x8*)&Bs[(nt * 16 + l16) * LDA + kk + quad * 8];
#pragma unroll
                for (int mt = 0; mt < 4; mt++)
#pragma unroll
                    for (int nt = 0; nt < 4; nt++)
                        acc[mt][nt] = __builtin_amdgcn_mfma_f32_16x16x32_bf16(af[mt], bfr[nt], acc[mt][nt], 0, 0, 0);
            }
            __syncthreads();
        }

        // Epilogue: write exp(k) / v into kv_s (alias of As), accumulate row exp-sums.
#pragma unroll
        for (int mt = 0; mt < 4; mt++) {
#pragma unroll
            for (int reg = 0; reg < 4; reg++) {
                int o = w * 64 + mt * 16 + quad * 4 + reg;
#pragma unroll
                for (int nt = 0; nt < 4; nt++) {
                    float v = acc[mt][nt][reg];
                    if (isK) { v = __expf(v); sexpA[mt][reg] += v; }
                    kvs[o * LDA + nt * 16 + l16] = f2bf(v);
                }
            }
        }
        __syncthreads();

        // Context partial: wave w = head h. C_part += P(32x64n) @ V^T(64nx32).
        {
            int h = w;
#pragma unroll
            for (int nk = 0; nk < 64; nk += 32) {
                bf16x8 pa[2], vb[2];
#pragma unroll
                for (int dt = 0; dt < 2; dt++)
                    pa[dt] = *(const bf16x8*)&kvs[(h * 32 + dt * 16 + l16) * LDA + nk + quad * 8];
#pragma unroll
                for (int et = 0; et < 2; et++)
                    vb[et] = *(const bf16x8*)&kvs[(128 + h * 32 + et * 16 + l16) * LDA + nk + quad * 8];
#pragma unroll
                for (int dt = 0; dt < 2; dt++)
#pragma unroll
                    for (int et = 0; et < 2; et++)
                        cacc[dt][et] = __builtin_amdgcn_mfma_f32_16x16x32_bf16(pa[dt], vb[et], cacc[dt][et], 0, 0, 0);
            }
        }
        __syncthreads();  // guard kvs reads before next sub-tile overwrites As
    }

    // Write block-private partials (streaming, no contention).
    float* Cb = Cpart + ((size_t)(b * SLOTS + slot) * HEADS + w) * 1024;
#pragma unroll
    for (int dt = 0; dt < 2; dt++)
#pragma unroll
        for (int et = 0; et < 2; et++)
#pragma unroll
            for (int reg = 0; reg < 4; reg++) {
                int d = dt * 16 + quad * 4 + reg;
                int e = et * 16 + l16;
                Cb[d * 32 + e] = cacc[dt][et][reg];
            }
    if (isK) {
#pragma unroll
        for (int mt = 0; mt < 4; mt++)
#pragma unroll
            for (int reg = 0; reg < 4; reg++) {
                float s = sexpA[mt][reg];
                s += __shfl_xor(s, 1, 64);
                s += __shfl_xor(s, 2, 64);
                s += __shfl_xor(s, 4, 64);
                s += __shfl_xor(s, 8, 64);
                if (l16 == 0) {
                    int o = w * 64 + mt * 16 + quad * 4 + reg;  // k row index 0..127
                    Spart[((size_t)b * SLOTS + slot) * 128 + o] = s;
                }
            }
    }
}

// ---------------- K1b: reduce slots -> Cg, Sinv ----------------
// grid (4, HEADS, B), 256 threads. Block (q,h,b) reduces 256 ctx elems over SLOTS.
__global__ __launch_bounds__(256) void k_reduce(const float* __restrict__ Cpart,
                                                const float* __restrict__ Spart,
                                                float* __restrict__ Cg,     // [B][H][32*32]
                                                float* __restrict__ Sinv) { // [B][H][32]
    int q = blockIdx.x, h = blockIdx.y, b = blockIdx.z;
    int t = threadIdx.x;
    int e = q * 256 + t;
    float acc = 0.f;
#pragma unroll 4
    for (int sl = 0; sl < SLOTS; sl++)
        acc += Cpart[((size_t)(b * SLOTS + sl) * HEADS + h) * 1024 + e];
    Cg[((size_t)b * HEADS + h) * 1024 + e] = acc;
    if (q == 0 && t < 32) {
        float s = 0.f;
#pragma unroll 4
        for (int sl = 0; sl < SLOTS; sl++)
            s += Spart[((size_t)b * SLOTS + sl) * 128 + h * 32 + t];
        Sinv[((size_t)b * HEADS + h) * 32 + t] = 1.0f / s;
    }
}

// ---------------- K2: M[b] = (w_out ∘ ctx) @ W_q  (256x256 bf16 per batch) ----------------
// grid (16 o-tiles, B), 256 threads.
__global__ __launch_bounds__(256) void k_build_m(const float* __restrict__ w_out,
                                                 const float* __restrict__ w_qkv,
                                                 const float* __restrict__ Cg,
                                                 const float* __restrict__ Sinv,
                                                 unsigned short* __restrict__ Mb) {
    __shared__ float Arow[16][128];
    int ot = blockIdx.x;
    int b  = blockIdx.y;
    int t  = threadIdx.x;
    const float* Cb = Cg + (size_t)b * HEADS * 32 * 32;
    const float* Sb = Sinv + (size_t)b * HEADS * 32;
#pragma unroll
    for (int i = 0; i < 8; i++) {
        int ent = t + 256 * i;         // 2048 entries: 16 o x 128 hd
        int ol  = ent >> 7;
        int hd  = ent & 127;
        int h = hd >> 5, d = hd & 31;
        const float* wo = w_out + (size_t)(ot * 16 + ol) * HID + h * 32;
        const float* cc = Cb + (h * 32 + d) * 32;
        float s = 0.f;
#pragma unroll
        for (int e = 0; e < 32; e++) s += wo[e] * cc[e];
        Arow[ol][hd] = s * Sb[h * 32 + d];
    }
    __syncthreads();
    unsigned short* Mo = Mb + (size_t)b * CDIM * CDIM;
    // Stream w_qkv rows once; 16 per-ol accumulators in registers.
    int c = t;
    float s[16];
#pragma unroll
    for (int ol = 0; ol < 16; ol++) s[ol] = 0.f;
#pragma unroll 4
    for (int hd = 0; hd < 128; hd++) {
        float wv = w_qkv[(size_t)hd * CDIM + c];
#pragma unroll
        for (int ol = 0; ol < 16; ol++) s[ol] += Arow[ol][hd] * wv;
    }
#pragma unroll
    for (int ol = 0; ol < 16; ol++)
        Mo[(size_t)(ot * 16 + ol) * CDIM + c] = f2bf(s[ol]);
}

// ---------------- K3: out[b] = M[b] @ x[b] + b_out (256 x 128n tile) ----------------
__global__ __launch_bounds__(256, 2) void k_out_gemm(const unsigned short* __restrict__ Mb,
                                                     const unsigned short* __restrict__ xt,
                                                     const float* __restrict__ b_out,
                                                     float* __restrict__ out) {
    __shared__ __align__(16) unsigned short As[256 * LDA];  // 36 KB
    __shared__ __align__(16) unsigned short Bs[128 * LDA];  // 18 KB
    int n0 = blockIdx.x * 128;
    int b  = blockIdx.y;
    int t = threadIdx.x;
    int w = t >> 6, lane = t & 63, quad = lane >> 4, l16 = lane & 15;

    f32x4 acc[4][8];
#pragma unroll
    for (int i = 0; i < 4; i++)
#pragma unroll
        for (int j = 0; j < 8; j++) acc[i][j] = (f32x4){0.f, 0.f, 0.f, 0.f};

    const unsigned short* Ab = Mb + (size_t)b * CDIM * CDIM;
    const unsigned short* xb = xt + (size_t)b * NN * CDIM;

    for (int kt = 0; kt < 4; kt++) {
        int k0 = kt * 64;
        // stage A (M 256x64): 2048 x 16B, 8 per thread
#pragma unroll
        for (int i = 0; i < 8; i++) {
            int vid = t + 256 * i;
            int o   = vid >> 3;
            int kk  = (vid & 7) << 3;
            uint4 v = *(const uint4*)(Ab + (size_t)o * 256 + k0 + kk);
            *(uint4*)&As[o * LDA + kk] = v;
        }
        // stage B (xt 128n x 64k): 1024 x 16B, 4 per thread
#pragma unroll
        for (int i = 0; i < 4; i++) {
            int vid = t + 256 * i;
            int nl  = vid >> 3;
            int kk  = (vid & 7) << 3;
            uint4 v = *(const uint4*)(xb + (size_t)(n0 + nl) * CDIM + k0 + kk);
            *(uint4*)&Bs[nl * LDA + kk] = v;
        }
        __syncthreads();
#pragma unroll
        for (int kk = 0; kk < 64; kk += 32) {
            bf16x8 af[4], bfr[8];
#pragma unroll
            for (int mt = 0; mt < 4; mt++)
                af[mt] = *(const bf16x8*)&As[(w * 64 + mt * 16 + l16) * LDA + kk + quad * 8];
#pragma unroll
            for (int nt = 0; nt < 8; nt++)
                bfr[nt] = *(const bf16x8*)&Bs[(nt * 16 + l16) * LDA + kk + quad * 8];
#pragma unroll
            for (int mt = 0; mt < 4; mt++)
#pragma unroll
                for (int nt = 0; nt < 8; nt++)
                    acc[mt][nt] = __builtin_amdgcn_mfma_f32_16x16x32_bf16(af[mt], bfr[nt], acc[mt][nt], 0, 0, 0);
        }
        __syncthreads();
    }

    float* ob = out + (size_t)b * CDIM * NN;
#pragma unroll
    for (int mt = 0; mt < 4; mt++)
#pragma unroll
        for (int reg = 0; reg < 4; reg++) {
            int o = w * 64 + mt * 16 + quad * 4 + reg;
            float bo = b_out[o];
#pragma unroll
            for (int nt = 0; nt < 8; nt++)
                ob[(size_t)o * NN + n0 + nt * 16 + l16] = acc[mt][nt][reg] + bo;
        }
}

// ---------------- launch ----------------
extern "C" void kernel_launch(void* const* d_in, const int* in_sizes, int n_in,
                              void* d_out, int out_size, void* d_ws, size_t ws_size,
                              hipStream_t stream) {
    const float* x     = (const float*)d_in[0];
    const float* w_qkv = (const float*)d_in[1];
    const float* w_out = (const float*)d_in[2];
    const float* b_out = (const float*)d_in[3];
    float* out = (float*)d_out;

    char* ws = (char*)d_ws;
    const size_t off_xt    = 0;                          // 16*8192*256*2      = 67108864
    const size_t off_wkv   = off_xt + 67108864;          // 256*256*2          = 131072
    const size_t off_Cpart = off_wkv + 131072;           // 16*64*4*1024*4     = 16777216
    const size_t off_Spart = off_Cpart + 16777216;       // 16*64*128*4        = 524288
    const size_t off_Cg    = off_Spart + 524288;         // 16*4*1024*4        = 262144
    const size_t off_Sinv  = off_Cg + 262144;            // 16*4*32*4          = 8192
    const size_t off_M     = off_Sinv + 8192;            // 16*256*256*2       = 2097152

    unsigned short* xt    = (unsigned short*)(ws + off_xt);
    unsigned short* wkv   = (unsigned short*)(ws + off_wkv);
    float*          Cpart = (float*)(ws + off_Cpart);
    float*          Spart = (float*)(ws + off_Spart);
    float*          Cg    = (float*)(ws + off_Cg);
    float*          Sinv  = (float*)(ws + off_Sinv);
    unsigned short* Mb    = (unsigned short*)(ws + off_M);

    k_transpose<<<dim3(NN / 64, CDIM / 64, BB), 256, 0, stream>>>(x, xt);
    k_convert_w<<<dim3(64), 256, 0, stream>>>(w_qkv, wkv);
    k_qkv_ctx<<<dim3(SLOTS, BB), 256, 0, stream>>>(wkv, xt, Cpart, Spart);
    k_reduce<<<dim3(4, HEADS, BB), 256, 0, stream>>>(Cpart, Spart, Cg, Sinv);
    k_build_m<<<dim3(16, BB), 256, 0, stream>>>(w_out, w_qkv, Cg, Sinv, Mb);
    k_out_gemm<<<dim3(NN / 128, BB), 256, 0, stream>>>(Mb, xt, b_out, out);
}